// Round 1
// baseline (232.008 us; speedup 1.0000x reference)
//
#include <hip/hip_runtime.h>
#include <math.h>

#define Bn 16
#define Cn 256
#define Ln 16384
#define Mn 64
#define LN_EPS 1e-5f

// K1: logits[b][l] = sum_c x[b][c][l]*w_mask[c] + b_mask
// grid (Ln/512, Bn), block 256; each thread owns 2 consecutive l (float2)
__global__ void k_logits(const float* __restrict__ x, const float* __restrict__ w_mask,
                         const float* __restrict__ b_mask, float* __restrict__ logits) {
    __shared__ float wm[Cn];
    const int t = threadIdx.x;
    wm[t] = w_mask[t];              // blockDim.x == Cn == 256
    __syncthreads();
    const int b = blockIdx.y;
    const int l0 = blockIdx.x * 512 + t * 2;
    const float* xb = x + (size_t)b * Cn * Ln + l0;
    float2 acc = make_float2(0.f, 0.f);
    for (int c = 0; c < Cn; ++c) {
        float2 v = *(const float2*)(xb + (size_t)c * Ln);
        float w = wm[c];
        acc.x += v.x * w;
        acc.y += v.y * w;
    }
    const float bm = b_mask[0];
    acc.x += bm;
    acc.y += bm;
    *(float2*)(logits + b * Ln + l0) = acc;
}

// K2: attn[b][:] = softmax(logits[b][:]), one block per b
__global__ void k_softmax(const float* __restrict__ logits, float* __restrict__ attn) {
    const int b = blockIdx.x;
    const float* row = logits + b * Ln;
    float* arow = attn + b * Ln;
    const int t = threadIdx.x;      // 256 threads
    __shared__ float red[4];

    float m = -1e30f;
    for (int i = t; i < Ln; i += 256) m = fmaxf(m, row[i]);
    for (int off = 32; off; off >>= 1) m = fmaxf(m, __shfl_xor(m, off, 64));
    if ((t & 63) == 0) red[t >> 6] = m;
    __syncthreads();
    m = fmaxf(fmaxf(red[0], red[1]), fmaxf(red[2], red[3]));
    __syncthreads();

    float z = 0.f;
    for (int i = t; i < Ln; i += 256) z += expf(row[i] - m);
    for (int off = 32; off; off >>= 1) z += __shfl_xor(z, off, 64);
    if ((t & 63) == 0) red[t >> 6] = z;
    __syncthreads();
    z = red[0] + red[1] + red[2] + red[3];
    const float inv = 1.f / z;

    for (int i = t; i < Ln; i += 256) arow[i] = expf(row[i] - m) * inv;
}

// K3: ctx[b][c] = dot(x[b][c][:], attn[b][:]); one block per (b,c) row
__global__ void k_ctx(const float* __restrict__ x, const float* __restrict__ attn,
                      float* __restrict__ ctx) {
    const int bc = blockIdx.x;      // b*Cn + c
    const int b = bc >> 8;
    const float4* row = (const float4*)(x + (size_t)bc * Ln);
    const float4* arow = (const float4*)(attn + (size_t)b * Ln);
    const int t = threadIdx.x;      // 256 threads
    float acc = 0.f;
    for (int i = t; i < Ln / 4; i += 256) {
        float4 v = row[i];
        float4 w = arow[i];
        acc += v.x * w.x + v.y * w.y + v.z * w.z + v.w * w.w;
    }
    for (int off = 32; off; off >>= 1) acc += __shfl_xor(acc, off, 64);
    __shared__ float red[4];
    if ((t & 63) == 0) red[t >> 6] = acc;
    __syncthreads();
    if (t == 0) ctx[bc] = red[0] + red[1] + red[2] + red[3];
}

// K4: tiny MLP: h = relu(LN(ctx @ w1^T + b1)); add = h @ w2^T + b2
// one block (1 wave, 64 threads) per b; M=64 == wavefront
__global__ void k_mlp(const float* __restrict__ ctx, const float* __restrict__ w1,
                      const float* __restrict__ b1, const float* __restrict__ ln_g,
                      const float* __restrict__ ln_b, const float* __restrict__ w2,
                      const float* __restrict__ b2, float* __restrict__ add) {
    const int b = blockIdx.x;
    const int m = threadIdx.x;      // 64 threads, one per mid-channel
    const float* cb = ctx + b * Cn;
    float h = b1[m];
    for (int c = 0; c < Cn; ++c) h += cb[c] * w1[m * Cn + c];

    float mu = h;
    for (int off = 32; off; off >>= 1) mu += __shfl_xor(mu, off, 64);
    mu *= (1.f / 64.f);
    const float d = h - mu;
    float var = d * d;
    for (int off = 32; off; off >>= 1) var += __shfl_xor(var, off, 64);
    var *= (1.f / 64.f);
    h = d * rsqrtf(var + LN_EPS) * ln_g[m] + ln_b[m];
    h = fmaxf(h, 0.f);

    __shared__ float hs[Mn];
    hs[m] = h;
    __syncthreads();

    #pragma unroll
    for (int k = 0; k < 4; ++k) {
        const int c = m + k * 64;
        float a = b2[c];
        for (int j = 0; j < Mn; ++j) a += hs[j] * w2[c * Mn + j];
        add[b * Cn + c] = a;
    }
}

// K5: out[b][c][l] = x[b][c][l] + add[b][c]
// grid (Ln/4096, Bn*Cn), block 256, each thread 4 float4
__global__ void k_out(const float* __restrict__ x, const float* __restrict__ add,
                      float* __restrict__ out) {
    const int bc = blockIdx.y;
    const float a = add[bc];
    const size_t base = (size_t)bc * Ln + (size_t)blockIdx.x * 4096;
    const float4* xi = (const float4*)(x + base);
    float4* xo = (float4*)(out + base);
    const int t = threadIdx.x;
    #pragma unroll
    for (int k = 0; k < 4; ++k) {
        float4 v = xi[k * 256 + t];
        v.x += a; v.y += a; v.z += a; v.w += a;
        xo[k * 256 + t] = v;
    }
}

extern "C" void kernel_launch(void* const* d_in, const int* in_sizes, int n_in,
                              void* d_out, int out_size, void* d_ws, size_t ws_size,
                              hipStream_t stream) {
    const float* x      = (const float*)d_in[0];
    const float* w_mask = (const float*)d_in[1];
    const float* b_mask = (const float*)d_in[2];
    const float* w1     = (const float*)d_in[3];
    const float* b1     = (const float*)d_in[4];
    const float* ln_g   = (const float*)d_in[5];
    const float* ln_b   = (const float*)d_in[6];
    const float* w2     = (const float*)d_in[7];
    const float* b2     = (const float*)d_in[8];
    float* out = (float*)d_out;

    float* ws     = (float*)d_ws;
    float* logits = ws;                       // Bn*Ln floats
    float* attn   = ws + (size_t)Bn * Ln;     // Bn*Ln floats
    float* ctx    = ws + (size_t)2 * Bn * Ln; // Bn*Cn floats
    float* add    = ctx + Bn * Cn;            // Bn*Cn floats

    k_logits<<<dim3(Ln / 512, Bn), 256, 0, stream>>>(x, w_mask, b_mask, logits);
    k_softmax<<<Bn, 256, 0, stream>>>(logits, attn);
    k_ctx<<<Bn * Cn, 256, 0, stream>>>(x, attn, ctx);
    k_mlp<<<Bn, Mn, 0, stream>>>(ctx, w1, b1, ln_g, ln_b, w2, b2, add);
    k_out<<<dim3(Ln / 4096, Bn * Cn), 256, 0, stream>>>(x, add, out);
}

// Round 2
// 201.362 us; speedup vs baseline: 1.1522x; 1.1522x over previous
//
#include <hip/hip_runtime.h>
#include <math.h>

#define Bn 16
#define Cn 256
#define Ln 16384
#define Mn 64
#define LN_EPS 1e-5f
#define CHUNK 1024
#define NCH (Ln / CHUNK)   // 16

// K1: fused logits + chunk-softmax + weighted pooling.
// grid (NCH, Bn), block 256. Per block: chunk of 1024 l-values of batch b.
// Phase A: logit[l] = sum_c x[b][c][l]*wm[c] + bm (coalesced float4 over l).
//          chunk max m, e[l] = exp(logit-m) in LDS, chunk sum Z.
// Phase B: ctxU[b][ch][c] = sum_{l in chunk} x[b][c][l]*e[l]  (re-read hits L2/L3).
__global__ void k_pass1(const float* __restrict__ x, const float* __restrict__ w_mask,
                        const float* __restrict__ b_mask,
                        float* __restrict__ ctxU,   // [Bn][NCH][Cn]
                        float* __restrict__ mz) {   // [Bn][NCH][2]
    const int ch = blockIdx.x, b = blockIdx.y;
    const int t = threadIdx.x;   // 256
    const size_t xbase = (size_t)b * Cn * Ln + (size_t)ch * CHUNK;
    __shared__ float wm[Cn];
    __shared__ float e[CHUNK];
    __shared__ float red[8];
    wm[t] = w_mask[t];
    __syncthreads();

    // ---- phase A ----
    float4 acc = make_float4(0.f, 0.f, 0.f, 0.f);
    const float* xp = x + xbase + 4 * t;
    #pragma unroll 8
    for (int c = 0; c < Cn; ++c) {
        float4 v = *(const float4*)(xp + (size_t)c * Ln);
        const float w = wm[c];
        acc.x += v.x * w; acc.y += v.y * w; acc.z += v.z * w; acc.w += v.w * w;
    }
    const float bm = b_mask[0];
    acc.x += bm; acc.y += bm; acc.z += bm; acc.w += bm;

    float lm = fmaxf(fmaxf(acc.x, acc.y), fmaxf(acc.z, acc.w));
    for (int off = 32; off; off >>= 1) lm = fmaxf(lm, __shfl_xor(lm, off, 64));
    if ((t & 63) == 0) red[t >> 6] = lm;
    __syncthreads();
    const float m = fmaxf(fmaxf(red[0], red[1]), fmaxf(red[2], red[3]));

    float4 ev;
    ev.x = expf(acc.x - m); ev.y = expf(acc.y - m);
    ev.z = expf(acc.z - m); ev.w = expf(acc.w - m);
    *(float4*)(e + 4 * t) = ev;
    float lz = ev.x + ev.y + ev.z + ev.w;
    for (int off = 32; off; off >>= 1) lz += __shfl_xor(lz, off, 64);
    if ((t & 63) == 0) red[4 + (t >> 6)] = lz;
    __syncthreads();   // e[] and red[4..7] now visible to all
    if (t == 0) {
        mz[(b * NCH + ch) * 2 + 0] = m;
        mz[(b * NCH + ch) * 2 + 1] = red[4] + red[5] + red[6] + red[7];
    }

    // ---- phase B ---- wave wv handles c = wv + 4k; lanes split the 1024 l's
    const int wv = t >> 6, lane = t & 63;
    for (int k = 0; k < 64; ++k) {
        const int c = wv + 4 * k;
        const float* xr = x + xbase + (size_t)c * Ln;
        float s = 0.f;
        #pragma unroll
        for (int j = 0; j < 4; ++j) {
            const int idx = (lane + j * 64) * 4;
            float4 v = *(const float4*)(xr + idx);
            float4 w = *(const float4*)(e + idx);
            s += v.x * w.x + v.y * w.y + v.z * w.z + v.w * w.w;
        }
        for (int off = 32; off; off >>= 1) s += __shfl_xor(s, off, 64);
        if (lane == 0) ctxU[((size_t)b * NCH + ch) * Cn + c] = s;
    }
}

// K2: combine chunk partials (flash renorm) -> ctx, then tiny MLP -> add.
// grid Bn, block 256.
__global__ void k_mlp(const float* __restrict__ ctxU, const float* __restrict__ mz,
                      const float* __restrict__ w1, const float* __restrict__ b1,
                      const float* __restrict__ ln_g, const float* __restrict__ ln_b,
                      const float* __restrict__ w2, const float* __restrict__ b2,
                      float* __restrict__ add) {
    const int b = blockIdx.x;
    const int t = threadIdx.x;   // 256
    __shared__ float ctx_s[Cn];
    __shared__ float h_s[Mn];

    float mloc[NCH], zloc[NCH], sc[NCH];
    float M = -1e30f;
    #pragma unroll
    for (int ch = 0; ch < NCH; ++ch) {
        mloc[ch] = mz[(b * NCH + ch) * 2 + 0];
        zloc[ch] = mz[(b * NCH + ch) * 2 + 1];
        M = fmaxf(M, mloc[ch]);
    }
    float Zg = 0.f;
    #pragma unroll
    for (int ch = 0; ch < NCH; ++ch) { sc[ch] = expf(mloc[ch] - M); Zg += zloc[ch] * sc[ch]; }
    float s = 0.f;
    #pragma unroll
    for (int ch = 0; ch < NCH; ++ch) s += ctxU[((size_t)b * NCH + ch) * Cn + t] * sc[ch];
    ctx_s[t] = s / Zg;
    __syncthreads();

    // h[m] = b1[m] + sum_c ctx[c]*w1[m][c]; 4 threads per m
    const int m4 = t >> 2, j = t & 3;
    float hp = 0.f;
    for (int c = j; c < Cn; c += 4) hp += ctx_s[c] * w1[m4 * Cn + c];
    hp += __shfl_xor(hp, 1, 64);
    hp += __shfl_xor(hp, 2, 64);
    if (j == 0) h_s[m4] = hp + b1[m4];
    __syncthreads();

    // LayerNorm + ReLU over the 64 mid-channels on wave 0
    if (t < 64) {
        float h = h_s[t];
        float mu = h;
        for (int off = 32; off; off >>= 1) mu += __shfl_xor(mu, off, 64);
        mu *= (1.f / 64.f);
        const float d = h - mu;
        float var = d * d;
        for (int off = 32; off; off >>= 1) var += __shfl_xor(var, off, 64);
        var *= (1.f / 64.f);
        h = d * rsqrtf(var + LN_EPS) * ln_g[t] + ln_b[t];
        h_s[t] = fmaxf(h, 0.f);
    }
    __syncthreads();

    float a = b2[t];
    #pragma unroll
    for (int mm = 0; mm < Mn; ++mm) a += h_s[mm] * w2[t * Mn + mm];
    add[b * Cn + t] = a;
}

// K3: out[b][c][l] = x[b][c][l] + add[b][c]
// grid (Ln/4096, Bn*Cn), block 256, each thread 4 float4
__global__ void k_out(const float* __restrict__ x, const float* __restrict__ add,
                      float* __restrict__ out) {
    const int bc = blockIdx.y;
    const float a = add[bc];
    const size_t base = (size_t)bc * Ln + (size_t)blockIdx.x * 4096;
    const float4* xi = (const float4*)(x + base);
    float4* xo = (float4*)(out + base);
    const int t = threadIdx.x;
    #pragma unroll
    for (int k = 0; k < 4; ++k) {
        float4 v = xi[k * 256 + t];
        v.x += a; v.y += a; v.z += a; v.w += a;
        xo[k * 256 + t] = v;
    }
}

extern "C" void kernel_launch(void* const* d_in, const int* in_sizes, int n_in,
                              void* d_out, int out_size, void* d_ws, size_t ws_size,
                              hipStream_t stream) {
    const float* x      = (const float*)d_in[0];
    const float* w_mask = (const float*)d_in[1];
    const float* b_mask = (const float*)d_in[2];
    const float* w1     = (const float*)d_in[3];
    const float* b1     = (const float*)d_in[4];
    const float* ln_g   = (const float*)d_in[5];
    const float* ln_b   = (const float*)d_in[6];
    const float* w2     = (const float*)d_in[7];
    const float* b2     = (const float*)d_in[8];
    float* out = (float*)d_out;

    float* ws   = (float*)d_ws;
    float* ctxU = ws;                                  // Bn*NCH*Cn = 65536 floats
    float* mz   = ctxU + (size_t)Bn * NCH * Cn;        // Bn*NCH*2  = 512 floats
    float* add  = mz + (size_t)Bn * NCH * 2;           // Bn*Cn     = 4096 floats

    k_pass1<<<dim3(NCH, Bn), 256, 0, stream>>>(x, w_mask, b_mask, ctxU, mz);
    k_mlp<<<Bn, 256, 0, stream>>>(ctxU, mz, w1, b1, ln_g, ln_b, w2, b2, add);
    k_out<<<dim3(Ln / 4096, Bn * Cn), 256, 0, stream>>>(x, add, out);
}

// Round 4
// 178.373 us; speedup vs baseline: 1.3007x; 1.1289x over previous
//
#include <hip/hip_runtime.h>
#include <math.h>

#define Bn 16
#define Cn 256
#define Ln 16384
#define Mn 64
#define LN_EPS 1e-5f
#define CHUNK 1024
#define NCH (Ln / CHUNK)   // 16

typedef float v4f __attribute__((ext_vector_type(4)));

// K1: logits + chunk-local softmax numerator.
// grid (NCH, Bn), block 256; thread owns one float4 of l.
// e_ws[b][l] = exp(logit[l] - m_chunk);  mz[b][ch] = (m_chunk, Z_chunk)
__global__ void k_logits(const float* __restrict__ x, const float* __restrict__ w_mask,
                         const float* __restrict__ b_mask,
                         float* __restrict__ e_ws, float* __restrict__ mz) {
    const int ch = blockIdx.x, b = blockIdx.y;
    const int t = threadIdx.x;   // 256
    const size_t xbase = (size_t)b * Cn * Ln + (size_t)ch * CHUNK;
    __shared__ float wm[Cn];
    __shared__ float red[8];
    wm[t] = w_mask[t];
    __syncthreads();

    float4 acc = make_float4(0.f, 0.f, 0.f, 0.f);
    const float* xp = x + xbase + 4 * t;
    #pragma unroll 8
    for (int c = 0; c < Cn; ++c) {
        float4 v = *(const float4*)(xp + (size_t)c * Ln);
        const float w = wm[c];
        acc.x += v.x * w; acc.y += v.y * w; acc.z += v.z * w; acc.w += v.w * w;
    }
    const float bm = b_mask[0];
    acc.x += bm; acc.y += bm; acc.z += bm; acc.w += bm;

    float lm = fmaxf(fmaxf(acc.x, acc.y), fmaxf(acc.z, acc.w));
    for (int off = 32; off; off >>= 1) lm = fmaxf(lm, __shfl_xor(lm, off, 64));
    if ((t & 63) == 0) red[t >> 6] = lm;
    __syncthreads();
    const float m = fmaxf(fmaxf(red[0], red[1]), fmaxf(red[2], red[3]));

    float4 ev;
    ev.x = expf(acc.x - m); ev.y = expf(acc.y - m);
    ev.z = expf(acc.z - m); ev.w = expf(acc.w - m);
    *(float4*)(e_ws + (size_t)b * Ln + ch * CHUNK + 4 * t) = ev;

    float lz = ev.x + ev.y + ev.z + ev.w;
    for (int off = 32; off; off >>= 1) lz += __shfl_xor(lz, off, 64);
    if ((t & 63) == 0) red[4 + (t >> 6)] = lz;
    __syncthreads();
    if (t == 0) {
        mz[(b * NCH + ch) * 2 + 0] = m;
        mz[(b * NCH + ch) * 2 + 1] = red[4] + red[5] + red[6] + red[7];
    }
}

// K2: ctx[b][c] = sum_l x[b][c][l] * softmax(l), via per-chunk rescale.
// grid Bn*Cn blocks, 256 threads; thread iteration j covers exactly chunk j.
__global__ void k_ctx(const float* __restrict__ x, const float* __restrict__ e_ws,
                      const float* __restrict__ mz, float* __restrict__ ctx) {
    const int bc = blockIdx.x;
    const int b = bc >> 8;
    const int t = threadIdx.x;   // 256

    // per-chunk scales: sc[j] = exp(m_j - M) / Z_total  (exact flash combine)
    float mloc[NCH], zloc[NCH], sc[NCH];
    float M = -1e30f;
    #pragma unroll
    for (int j = 0; j < NCH; ++j) {
        mloc[j] = mz[(b * NCH + j) * 2 + 0];
        zloc[j] = mz[(b * NCH + j) * 2 + 1];
        M = fmaxf(M, mloc[j]);
    }
    float Z = 0.f;
    #pragma unroll
    for (int j = 0; j < NCH; ++j) { sc[j] = expf(mloc[j] - M); Z += zloc[j] * sc[j]; }
    const float invZ = 1.f / Z;
    #pragma unroll
    for (int j = 0; j < NCH; ++j) sc[j] *= invZ;

    const float4* row  = (const float4*)(x + (size_t)bc * Ln);
    const float4* erow = (const float4*)(e_ws + (size_t)b * Ln);
    float acc = 0.f;
    #pragma unroll
    for (int j = 0; j < NCH; ++j) {           // float4 index t + j*256 -> l in chunk j
        float4 v = row[t + j * 256];
        float4 w = erow[t + j * 256];
        acc += sc[j] * (v.x * w.x + v.y * w.y + v.z * w.z + v.w * w.w);
    }
    for (int off = 32; off; off >>= 1) acc += __shfl_xor(acc, off, 64);
    __shared__ float red[4];
    if ((t & 63) == 0) red[t >> 6] = acc;
    __syncthreads();
    if (t == 0) ctx[bc] = red[0] + red[1] + red[2] + red[3];
}

// K3: tiny MLP: h = relu(LN(ctx @ w1^T + b1)); add = h @ w2^T + b2. grid Bn, block 256.
__global__ void k_mlp(const float* __restrict__ ctx, const float* __restrict__ w1,
                      const float* __restrict__ b1, const float* __restrict__ ln_g,
                      const float* __restrict__ ln_b, const float* __restrict__ w2,
                      const float* __restrict__ b2, float* __restrict__ add) {
    const int b = blockIdx.x;
    const int t = threadIdx.x;   // 256
    __shared__ float ctx_s[Cn];
    __shared__ float h_s[Mn];
    ctx_s[t] = ctx[b * Cn + t];
    __syncthreads();

    const int m4 = t >> 2, j = t & 3;
    float hp = 0.f;
    for (int c = j; c < Cn; c += 4) hp += ctx_s[c] * w1[m4 * Cn + c];
    hp += __shfl_xor(hp, 1, 64);
    hp += __shfl_xor(hp, 2, 64);
    if (j == 0) h_s[m4] = hp + b1[m4];
    __syncthreads();

    if (t < 64) {
        float h = h_s[t];
        float mu = h;
        for (int off = 32; off; off >>= 1) mu += __shfl_xor(mu, off, 64);
        mu *= (1.f / 64.f);
        const float d = h - mu;
        float var = d * d;
        for (int off = 32; off; off >>= 1) var += __shfl_xor(var, off, 64);
        var *= (1.f / 64.f);
        h = d * rsqrtf(var + LN_EPS) * ln_g[t] + ln_b[t];
        h_s[t] = fmaxf(h, 0.f);
    }
    __syncthreads();

    float a = b2[t];
    #pragma unroll
    for (int mm = 0; mm < Mn; ++mm) a += h_s[mm] * w2[t * Mn + mm];
    add[b * Cn + t] = a;
}

// K4: out = x + add broadcast. Nontemporal stores keep x resident in L3.
// grid (Ln/4096, Bn*Cn), block 256, each thread 4 float4.
__global__ void k_out(const float* __restrict__ x, const float* __restrict__ add,
                      float* __restrict__ out) {
    const int bc = blockIdx.y;
    const float a = add[bc];
    const size_t base = (size_t)bc * Ln + (size_t)blockIdx.x * 4096;
    const float4* xi = (const float4*)(x + base);
    v4f* xo = (v4f*)(out + base);
    const int t = threadIdx.x;
    #pragma unroll
    for (int k = 0; k < 4; ++k) {
        float4 v = xi[k * 256 + t];
        v4f o = {v.x + a, v.y + a, v.z + a, v.w + a};
        __builtin_nontemporal_store(o, xo + k * 256 + t);
    }
}

extern "C" void kernel_launch(void* const* d_in, const int* in_sizes, int n_in,
                              void* d_out, int out_size, void* d_ws, size_t ws_size,
                              hipStream_t stream) {
    const float* x      = (const float*)d_in[0];
    const float* w_mask = (const float*)d_in[1];
    const float* b_mask = (const float*)d_in[2];
    const float* w1     = (const float*)d_in[3];
    const float* b1     = (const float*)d_in[4];
    const float* ln_g   = (const float*)d_in[5];
    const float* ln_b   = (const float*)d_in[6];
    const float* w2     = (const float*)d_in[7];
    const float* b2     = (const float*)d_in[8];
    float* out = (float*)d_out;

    float* ws   = (float*)d_ws;
    float* e_ws = ws;                                  // Bn*Ln = 262144 floats (1 MiB)
    float* mz   = e_ws + (size_t)Bn * Ln;              // Bn*NCH*2 = 512 floats
    float* ctx  = mz + (size_t)Bn * NCH * 2;           // Bn*Cn = 4096 floats
    float* add  = ctx + (size_t)Bn * Cn;               // Bn*Cn = 4096 floats

    k_logits<<<dim3(NCH, Bn), 256, 0, stream>>>(x, w_mask, b_mask, e_ws, mz);
    k_ctx<<<Bn * Cn, 256, 0, stream>>>(x, e_ws, mz, ctx);
    k_mlp<<<Bn, 256, 0, stream>>>(ctx, w1, b1, ln_g, ln_b, w2, b2, add);
    k_out<<<dim3(Ln / 4096, Bn * Cn), 256, 0, stream>>>(x, add, out);
}